// Round 4
// baseline (111648.206 us; speedup 1.0000x reference)
//
#include <hip/hip_runtime.h>

#define TSTEPS 1920
#define NB 128
#define HIDN 256
#define LATN 128
#define EPSF 1e-5f

typedef __attribute__((ext_vector_type(8))) short bf16x8;
typedef __attribute__((ext_vector_type(4))) float f32x4;

__device__ __forceinline__ unsigned short f2bf(float x) {
    unsigned u = __builtin_bit_cast(unsigned, x);
    unsigned r = (u + 0x7fffu + ((u >> 16) & 1u)) >> 16;
    return (unsigned short)r;
}
__device__ __forceinline__ float bf2f(unsigned short h) {
    unsigned u = ((unsigned)h) << 16;
    return __builtin_bit_cast(float, u);
}
__device__ __forceinline__ float fsig(float x) {
    float e = __expf(-fabsf(x));
    float s = 1.f / (1.f + e);
    return x >= 0.f ? s : 1.f - s;
}
__device__ __forceinline__ float ftanh(float x) {
    float e = __expf(-2.f * fabsf(x));
    float r = (1.f - e) / (1.f + e);
    return x >= 0.f ? r : -r;
}
__device__ __forceinline__ float fleaky(float x) { return x > 0.f ? x : 0.2f * x; }
__device__ __forceinline__ bf16x8 bcast16(uint4 v) { return __builtin_bit_cast(bf16x8, v); }

__device__ __forceinline__ void spin_ge(unsigned* ctr, unsigned target) {
    while (__hip_atomic_load(ctr, __ATOMIC_RELAXED, __HIP_MEMORY_SCOPE_AGENT) < target) {
        __builtin_amdgcn_s_sleep(1);
    }
}
__device__ __forceinline__ void ctr_inc(unsigned* ctr) {
    __hip_atomic_fetch_add(ctr, 1u, __ATOMIC_RELAXED, __HIP_MEMORY_SCOPE_AGENT);
}

#define MFMA(a, b, c) __builtin_amdgcn_mfma_f32_16x16x32_bf16((a), (b), (c), 0, 0, 0)

// ---- init: zero group counters ----
__global__ void init_ctrs(unsigned* c) {
    if (threadIdx.x < 16) c[threadIdx.x] = 0u;
}

// ---- pack W [N][KA+KB] -> MFMA B-fragment order, split hi/lo bf16 ----
// tile = nt*KT + kt ; elem e = tile*512 + l*8 + j ; n = nt*16+(l&15) ; k = kt*32+(l>>4)*8+j
__global__ void pack_bf16_frag(const float* __restrict__ A, const float* __restrict__ Bsrc,
                               int N, int KA, int KB,
                               unsigned short* __restrict__ hi, unsigned short* __restrict__ lo) {
    int e = blockIdx.x * 256 + threadIdx.x;
    int K = KA + KB;
    if (e >= N * K) return;
    int j = e & 7;
    int l = (e >> 3) & 63;
    int tile = e >> 9;
    int KT = K >> 5;
    int kt = tile % KT, nt = tile / KT;
    int n = nt * 16 + (l & 15);
    int k = kt * 32 + (l >> 4) * 8 + j;
    float v = (k < KA) ? A[n * KA + k] : Bsrc[n * KB + (k - KA)];
    unsigned short h = f2bf(v);
    hi[e] = h;
    lo[e] = f2bf(v - bf2f(h));
}

// ---- pack fp32 [N][K] -> [k4][n][4] for xw0 GEMV ----
__global__ void pack4T(const float* __restrict__ W, int N, int K, float* __restrict__ out) {
    int e = blockIdx.x * 256 + threadIdx.x;
    if (e >= N * K) return;
    int j = e & 3;
    int rest = e >> 2;
    int n = rest % N;
    int k4 = rest / N;
    out[e] = W[n * K + 4 * k4 + j];
}

__global__ void prep_b1(const float* __restrict__ bih1, const float* __restrict__ bhh1,
                        float* __restrict__ b1sum) {
    int i = blockIdx.x * 256 + threadIdx.x;
    if (i < 1024) b1sum[i] = bih1[i] + bhh1[i];
}

// ---- np head: embedding + MLP + LN + leaky -> x_const [B][512] ----
__global__ void np_head(const float* __restrict__ z, const int* __restrict__ labels,
                        const float* __restrict__ emb_W, const float* __restrict__ np_W,
                        const float* __restrict__ np_b, const float* __restrict__ np_g,
                        const float* __restrict__ np_be, float* __restrict__ x_const) {
    int b = blockIdx.x;
    int j = threadIdx.x;  // 0..255
    __shared__ float xc[LATN + HIDN];
    __shared__ float red[8];
    int lab = labels[b];
    if (j < LATN) xc[j] = z[b * LATN + j];
    float e = emb_W[lab * HIDN + j];
    xc[LATN + j] = e;
    __syncthreads();
    float d = np_b[j];
    for (int k = 0; k < LATN + HIDN; ++k) d += xc[k] * np_W[j * (LATN + HIDN) + k];
    int lane = j & 63, wv = j >> 6;
    float s = d, s2 = d * d;
    for (int o = 1; o < 64; o <<= 1) { s += __shfl_xor(s, o); s2 += __shfl_xor(s2, o); }
    if (lane == 0) { red[wv] = s; red[4 + wv] = s2; }
    __syncthreads();
    float S = red[0] + red[1] + red[2] + red[3];
    float S2 = red[4] + red[5] + red[6] + red[7];
    float m = S * (1.f / 256.f);
    float var = S2 * (1.f / 256.f) - m * m;
    float h = fleaky((d - m) * rsqrtf(var + EPSF) * np_g[j] + np_be[j]);
    x_const[b * 512 + j] = h;
    x_const[b * 512 + 256 + j] = e;
}

// ---- xw0[b][g] = bih0+bhh0 + x_const[b] . Wih0[g]  (fp32) ----
__global__ void __launch_bounds__(1024) xw0_kernel(const float* __restrict__ x_const,
                                                   const float4* __restrict__ Wih0T4,
                                                   const float* __restrict__ bih0,
                                                   const float* __restrict__ bhh0,
                                                   float* __restrict__ xw0) {
    int b = blockIdx.x;
    int g = threadIdx.x;
    __shared__ float xc[512];
    if (g < 512) xc[g] = x_const[b * 512 + g];
    __syncthreads();
    const float4* xc4 = (const float4*)xc;
    float4 acc = {0.f, 0.f, 0.f, 0.f};
#pragma unroll 8
    for (int k4 = 0; k4 < 128; ++k4) {
        float4 w = Wih0T4[k4 * 1024 + g];
        float4 x = xc4[k4];
        acc.x = fmaf(w.x, x.x, acc.x);
        acc.y = fmaf(w.y, x.y, acc.y);
        acc.z = fmaf(w.z, x.z, acc.z);
        acc.w = fmaf(w.w, x.w, acc.w);
    }
    xw0[b * 1024 + g] = bih0[g] + bhh0[g] + ((acc.x + acc.y) + (acc.z + acc.w));
}

// ---- split recurrent kernel: 64 blocks = 8 groups x 8 slices, 192 thr (2 rec + 1 head wave) ----
// hbuf layout: [g][layer][buf][hl][row16][k256] u16
__global__ void __launch_bounds__(192) lstm_split(
    const uint4* __restrict__ whh0h, const uint4* __restrict__ whh0l,
    const uint4* __restrict__ w1h, const uint4* __restrict__ w1l,
    const float* __restrict__ sW1, const float* __restrict__ xw0g,
    const float* __restrict__ b1sum, const float* __restrict__ sb1,
    const float* __restrict__ sg, const float* __restrict__ sbe,
    const float* __restrict__ sW2, const float* __restrict__ sb2,
    unsigned short* __restrict__ hbuf, unsigned* __restrict__ ctrs,
    float* __restrict__ base_out, float* __restrict__ hsum_out) {
    extern __shared__ float sw1s[];  // 128*256 fp32, XOR-swizzled
    const int blk = blockIdx.x;
    const int g = blk >> 3;
    const int w = blk & 7;
    const int tid = threadIdx.x;
    const int l = tid & 63;
    const int wave = tid >> 6;  // 0,1 = recurrence; 2 = head
    const int ln16 = l & 15;
    const int kg = l >> 4;

    unsigned* ctr0 = ctrs + g * 2;
    unsigned* ctr1 = ctrs + g * 2 + 1;

    // stage sW1 fp32 -> swizzled LDS (all waves)
    for (int i = tid; i < 128 * 256; i += 192) {
        int j = i >> 8, k = i & 255;
        sw1s[(j << 8) + (k ^ ((j & 63) << 2))] = sW1[i];
    }

#define HBUF(layer, buf, hl) (hbuf + ((((g * 2 + (layer)) * 2 + (buf)) * 2 + (hl)) * 4096))

    // zero own h slices in both buffers (rec waves)
    if (wave < 2) {
        int u = 32 * w + 16 * wave + ln16;
#pragma unroll
        for (int layer = 0; layer < 2; ++layer)
#pragma unroll
            for (int buf = 0; buf < 2; ++buf)
#pragma unroll
                for (int hl = 0; hl < 2; ++hl)
                    for (int mm = 0; mm < 4; ++mm)
                        HBUF(layer, buf, hl)[(kg * 4 + mm) * 256 + u] = 0;
    }
    __syncthreads();
    __threadfence();
    if (l == 0) {
        ctr_inc(ctr0);
        if (wave < 2) ctr_inc(ctr1);
    }
    spin_ge(ctr0, 24u);
    spin_ge(ctr1, 16u);
    __threadfence();

    if (wave < 2) {
        // ================= RECURRENCE WAVE =================
        const int v = wave;
        const int u = 32 * w + 16 * v + ln16;
        // B-fragment index bases: nt = 2w + 16*gidx + v
        int b0idx[4], c0idx[4], c1idx[4];
#pragma unroll
        for (int gi = 0; gi < 4; ++gi) {
            int nt = 2 * w + 16 * gi + v;
            b0idx[gi] = nt * 8 * 64 + l;        // layer0, KT=8
            c0idx[gi] = nt * 16 * 64 + l;       // layer1, kt 0..7
            c1idx[gi] = (nt * 16 + 8) * 64 + l; // layer1, kt 8..15
        }
        // hoisted per-lane constants
        f32x4 xwi[4];
        float b1v[4];
#pragma unroll
        for (int gi = 0; gi < 4; ++gi) {
            int n = 256 * gi + 32 * w + 16 * v + ln16;
            b1v[gi] = b1sum[n];
#pragma unroll
            for (int r = 0; r < 4; ++r)
                xwi[gi][r] = xw0g[(g * 16 + kg * 4 + r) * 1024 + n];
        }
        float c0s[4] = {0.f, 0.f, 0.f, 0.f};
        float c1s[4] = {0.f, 0.f, 0.f, 0.f};
        float hs[4] = {0.f, 0.f, 0.f, 0.f};
        const int aoffb = ln16 * 256 + kg * 8;

        for (int t = 0; t < TSTEPS; ++t) {
            const int cur = t & 1, prev = cur ^ 1;
            // ---- MV0: gates0 = xw0 + Whh0 @ h0(t-1) ----
            f32x4 a0 = xwi[0], a1 = xwi[1], a2 = xwi[2], a3 = xwi[3];
            {
                const unsigned short* ph = HBUF(0, prev, 0);
                const unsigned short* pl = HBUF(0, prev, 1);
#pragma unroll 2
                for (int kt = 0; kt < 8; ++kt) {
                    bf16x8 ahi = bcast16(*(const uint4*)(ph + aoffb + kt * 32));
                    bf16x8 alo = bcast16(*(const uint4*)(pl + aoffb + kt * 32));
                    bf16x8 bh, bl;
                    bh = bcast16(whh0h[b0idx[0] + kt * 64]); bl = bcast16(whh0l[b0idx[0] + kt * 64]);
                    a0 = MFMA(ahi, bh, a0); a0 = MFMA(alo, bh, a0); a0 = MFMA(ahi, bl, a0);
                    bh = bcast16(whh0h[b0idx[1] + kt * 64]); bl = bcast16(whh0l[b0idx[1] + kt * 64]);
                    a1 = MFMA(ahi, bh, a1); a1 = MFMA(alo, bh, a1); a1 = MFMA(ahi, bl, a1);
                    bh = bcast16(whh0h[b0idx[2] + kt * 64]); bl = bcast16(whh0l[b0idx[2] + kt * 64]);
                    a2 = MFMA(ahi, bh, a2); a2 = MFMA(alo, bh, a2); a2 = MFMA(ahi, bl, a2);
                    bh = bcast16(whh0h[b0idx[3] + kt * 64]); bl = bcast16(whh0l[b0idx[3] + kt * 64]);
                    a3 = MFMA(ahi, bh, a3); a3 = MFMA(alo, bh, a3); a3 = MFMA(ahi, bl, a3);
                }
            }
            // ---- UPD0: write h0(t) own slice ----
            {
                unsigned short* dh = HBUF(0, cur, 0);
                unsigned short* dl = HBUF(0, cur, 1);
#pragma unroll
                for (int r = 0; r < 4; ++r) {
                    float i_ = a0[r], f_ = a1[r], g_ = a2[r], o_ = a3[r];
                    float c = fsig(f_) * c0s[r] + fsig(i_) * ftanh(g_);
                    c0s[r] = c;
                    float h = fsig(o_) * ftanh(c);
                    unsigned short hh = f2bf(h);
                    dh[(kg * 4 + r) * 256 + u] = hh;
                    dl[(kg * 4 + r) * 256 + u] = f2bf(h - bf2f(hh));
                }
            }
            __threadfence();
            if (l == 0) ctr_inc(ctr0);
            // ---- wait all h0(t) published (+ head(t-1) done) ----
            spin_ge(ctr0, 24u * (unsigned)t + 40u);
            __threadfence();
            // ---- MV1: gates1 = b1 + [Wih1|Whh1] @ [h0(t); h1(t-1)] ----
            a0 = (f32x4){b1v[0], b1v[0], b1v[0], b1v[0]};
            a1 = (f32x4){b1v[1], b1v[1], b1v[1], b1v[1]};
            a2 = (f32x4){b1v[2], b1v[2], b1v[2], b1v[2]};
            a3 = (f32x4){b1v[3], b1v[3], b1v[3], b1v[3]};
            {
                const unsigned short* ph = HBUF(0, cur, 0);
                const unsigned short* pl = HBUF(0, cur, 1);
#pragma unroll 2
                for (int kt = 0; kt < 8; ++kt) {
                    bf16x8 ahi = bcast16(*(const uint4*)(ph + aoffb + kt * 32));
                    bf16x8 alo = bcast16(*(const uint4*)(pl + aoffb + kt * 32));
                    bf16x8 bh, bl;
                    bh = bcast16(w1h[c0idx[0] + kt * 64]); bl = bcast16(w1l[c0idx[0] + kt * 64]);
                    a0 = MFMA(ahi, bh, a0); a0 = MFMA(alo, bh, a0); a0 = MFMA(ahi, bl, a0);
                    bh = bcast16(w1h[c0idx[1] + kt * 64]); bl = bcast16(w1l[c0idx[1] + kt * 64]);
                    a1 = MFMA(ahi, bh, a1); a1 = MFMA(alo, bh, a1); a1 = MFMA(ahi, bl, a1);
                    bh = bcast16(w1h[c0idx[2] + kt * 64]); bl = bcast16(w1l[c0idx[2] + kt * 64]);
                    a2 = MFMA(ahi, bh, a2); a2 = MFMA(alo, bh, a2); a2 = MFMA(ahi, bl, a2);
                    bh = bcast16(w1h[c0idx[3] + kt * 64]); bl = bcast16(w1l[c0idx[3] + kt * 64]);
                    a3 = MFMA(ahi, bh, a3); a3 = MFMA(alo, bh, a3); a3 = MFMA(ahi, bl, a3);
                }
                const unsigned short* qh = HBUF(1, prev, 0);
                const unsigned short* ql = HBUF(1, prev, 1);
#pragma unroll 2
                for (int kt = 0; kt < 8; ++kt) {
                    bf16x8 ahi = bcast16(*(const uint4*)(qh + aoffb + kt * 32));
                    bf16x8 alo = bcast16(*(const uint4*)(ql + aoffb + kt * 32));
                    bf16x8 bh, bl;
                    bh = bcast16(w1h[c1idx[0] + kt * 64]); bl = bcast16(w1l[c1idx[0] + kt * 64]);
                    a0 = MFMA(ahi, bh, a0); a0 = MFMA(alo, bh, a0); a0 = MFMA(ahi, bl, a0);
                    bh = bcast16(w1h[c1idx[1] + kt * 64]); bl = bcast16(w1l[c1idx[1] + kt * 64]);
                    a1 = MFMA(ahi, bh, a1); a1 = MFMA(alo, bh, a1); a1 = MFMA(ahi, bl, a1);
                    bh = bcast16(w1h[c1idx[2] + kt * 64]); bl = bcast16(w1l[c1idx[2] + kt * 64]);
                    a2 = MFMA(ahi, bh, a2); a2 = MFMA(alo, bh, a2); a2 = MFMA(ahi, bl, a2);
                    bh = bcast16(w1h[c1idx[3] + kt * 64]); bl = bcast16(w1l[c1idx[3] + kt * 64]);
                    a3 = MFMA(ahi, bh, a3); a3 = MFMA(alo, bh, a3); a3 = MFMA(ahi, bl, a3);
                }
            }
            // ---- UPD1: write h1(t), accumulate hsum ----
            {
                unsigned short* dh = HBUF(1, cur, 0);
                unsigned short* dl = HBUF(1, cur, 1);
#pragma unroll
                for (int r = 0; r < 4; ++r) {
                    float i_ = a0[r], f_ = a1[r], g_ = a2[r], o_ = a3[r];
                    float c = fsig(f_) * c1s[r] + fsig(i_) * ftanh(g_);
                    c1s[r] = c;
                    float h = fsig(o_) * ftanh(c);
                    hs[r] += h;
                    unsigned short hh = f2bf(h);
                    dh[(kg * 4 + r) * 256 + u] = hh;
                    dl[(kg * 4 + r) * 256 + u] = f2bf(h - bf2f(hh));
                }
            }
            __threadfence();
            if (l == 0) ctr_inc(ctr1);
        }
#pragma unroll
        for (int r = 0; r < 4; ++r)
            hsum_out[(g * 16 + kg * 4 + r) * HIDN + u] = hs[r];
    } else {
        // ================= HEAD WAVE (2 rows, lags one step) =================
        const int j0 = 2 * l, j1 = 2 * l + 1;
        const float sb1a = sb1[j0], sb1b = sb1[j1];
        const float sga = sg[j0], sgb = sg[j1];
        const float sbea = sbe[j0], sbeb = sbe[j1];
        const float sw2a = sW2[j0], sw2b = sW2[j1];
        const float sb2v = sb2[0];
        const int swa = (j0 & 63) << 2;
        const int swb = (j1 & 63) << 2;

        for (int t = 0; t < TSTEPS; ++t) {
            spin_ge(ctr1, 16u * (unsigned)t + 32u);
            __threadfence();
            const int cur = t & 1;
            const unsigned short* ph = HBUF(1, cur, 0);
            const unsigned short* pl = HBUF(1, cur, 1);
#pragma unroll
            for (int rr = 0; rr < 2; ++rr) {
                const int row = 2 * w + rr;
                float sA = sb1a, sB = sb1b;
#pragma unroll 4
                for (int kc = 0; kc < 32; ++kc) {
                    uint4 hi4 = *(const uint4*)(ph + row * 256 + kc * 8);
                    uint4 lo4 = *(const uint4*)(pl + row * 256 + kc * 8);
                    float h[8];
#pragma unroll
                    for (int q2 = 0; q2 < 4; ++q2) {
                        unsigned hv = ((const unsigned*)&hi4)[q2];
                        unsigned lv = ((const unsigned*)&lo4)[q2];
                        h[2 * q2] = __builtin_bit_cast(float, hv << 16) +
                                    __builtin_bit_cast(float, lv << 16);
                        h[2 * q2 + 1] = __builtin_bit_cast(float, hv & 0xFFFF0000u) +
                                        __builtin_bit_cast(float, lv & 0xFFFF0000u);
                    }
                    float4 wA0 = *(const float4*)&sw1s[(j0 << 8) + ((kc * 8) ^ swa)];
                    float4 wA1 = *(const float4*)&sw1s[(j0 << 8) + ((kc * 8 + 4) ^ swa)];
                    float4 wB0 = *(const float4*)&sw1s[(j1 << 8) + ((kc * 8) ^ swb)];
                    float4 wB1 = *(const float4*)&sw1s[(j1 << 8) + ((kc * 8 + 4) ^ swb)];
                    sA = fmaf(wA0.x, h[0], sA); sA = fmaf(wA0.y, h[1], sA);
                    sA = fmaf(wA0.z, h[2], sA); sA = fmaf(wA0.w, h[3], sA);
                    sA = fmaf(wA1.x, h[4], sA); sA = fmaf(wA1.y, h[5], sA);
                    sA = fmaf(wA1.z, h[6], sA); sA = fmaf(wA1.w, h[7], sA);
                    sB = fmaf(wB0.x, h[0], sB); sB = fmaf(wB0.y, h[1], sB);
                    sB = fmaf(wB0.z, h[2], sB); sB = fmaf(wB0.w, h[3], sB);
                    sB = fmaf(wB1.x, h[4], sB); sB = fmaf(wB1.y, h[5], sB);
                    sB = fmaf(wB1.z, h[6], sB); sB = fmaf(wB1.w, h[7], sB);
                }
                // LN over 128 (2 per lane) + leaky + dot sW2 + tanh
                float ssum = sA + sB, ssq = sA * sA + sB * sB;
#pragma unroll
                for (int o = 1; o < 64; o <<= 1) {
                    ssum += __shfl_xor(ssum, o);
                    ssq += __shfl_xor(ssq, o);
                }
                float m = ssum * (1.f / 128.f);
                float var = ssq * (1.f / 128.f) - m * m;
                float rstd = rsqrtf(var + EPSF);
                float p0 = fleaky((sA - m) * rstd * sga + sbea);
                float p1 = fleaky((sB - m) * rstd * sgb + sbeb);
                float q = p0 * sw2a + p1 * sw2b;
#pragma unroll
                for (int o = 1; o < 64; o <<= 1) q += __shfl_xor(q, o);
                if (l == 0) base_out[(g * 16 + row) * TSTEPS + t] = ftanh(q + sb2v);
            }
            __threadfence();
            if (l == 0) ctr_inc(ctr0);
        }
    }
#undef HBUF
}

// ---- final head + oscillator + smoothing + label select ----
__global__ void out_kernel(const float* __restrict__ hsum, const float* __restrict__ oW1,
                           const float* __restrict__ ob1, const float* __restrict__ og,
                           const float* __restrict__ obe, const float* __restrict__ oW2,
                           const float* __restrict__ ob2, const float* __restrict__ base,
                           const int* __restrict__ labels, const float* __restrict__ stress_w,
                           const float* __restrict__ amu_w, const float* __restrict__ amu_b,
                           float* __restrict__ out) {
    int b = blockIdx.x;
    int tid = threadIdx.x;  // 0..255
    int lane = tid & 63, wv = tid >> 6;
    __shared__ float havg[256];
    __shared__ float red[8];
    __shared__ float params[3];
    __shared__ float e_row[TSTEPS];
    havg[tid] = hsum[b * 256 + tid] * (1.f / (float)TSTEPS);
    __syncthreads();
    float d1 = 0.f;
    if (tid < 128) {
        d1 = ob1[tid];
        for (int k = 0; k < 256; ++k) d1 += havg[k] * oW1[tid * 256 + k];
    }
    float s = d1, s2 = d1 * d1;
    for (int o = 1; o < 64; o <<= 1) { s += __shfl_xor(s, o); s2 += __shfl_xor(s2, o); }
    if (lane == 0 && wv < 2) { red[wv] = s; red[2 + wv] = s2; }
    __syncthreads();
    float m = (red[0] + red[1]) * (1.f / 128.f);
    float var = (red[2] + red[3]) * (1.f / 128.f) - m * m;
    float rstd = rsqrtf(var + EPSF);
    float p = 0.f;
    if (tid < 128) p = fleaky((d1 - m) * rstd * og[tid] + obe[tid]);
    float q0 = tid < 128 ? p * oW2[0 * 128 + tid] : 0.f;
    float q1 = tid < 128 ? p * oW2[1 * 128 + tid] : 0.f;
    float q2 = tid < 128 ? p * oW2[2 * 128 + tid] : 0.f;
    for (int o = 1; o < 64; o <<= 1) {
        q0 += __shfl_xor(q0, o); q1 += __shfl_xor(q1, o); q2 += __shfl_xor(q2, o);
    }
    __syncthreads();
    if (lane == 0 && wv < 2) { red[wv] = q0; red[2 + wv] = q1; red[4 + wv] = q2; }
    __syncthreads();
    if (tid == 0) {
        float op0 = red[0] + red[1] + ob2[0];
        float op1 = red[2] + red[3] + ob2[1];
        float op2 = red[4] + red[5] + ob2[2];
        params[0] = 0.23f + 0.04f * ftanh(op0);
        params[1] = 2.0f + 1.5f * ftanh(op1);
        params[2] = 3.14159265358979f * fsig(op2);
    }
    __syncthreads();
    float freq = params[0], amp = params[1], ph = params[2];
    for (int t = tid; t < TSTEPS; t += 256) {
        float x = freq * ((float)TSTEPS * (float)t / (float)(TSTEPS - 1));
        x -= floorf(x);
        float osc = amp * __sinf(6.28318530717958647f * x + ph);
        e_row[t] = 0.6f * base[b * TSTEPS + t] + 0.4f * osc;
    }
    __syncthreads();
    int lab = labels[b];
    float sw = stress_w[0];
    float w0 = amu_w[0], w1 = amu_w[1], w2 = amu_w[2], ab = amu_b[0];
    for (int t = tid; t < TSTEPS; t += 256) {
        float e = e_row[t];
        float r;
        if (lab == 1) r = e;
        else if (lab == 2) r = sw * e;
        else if (lab == 3) {
            float em = t > 0 ? e_row[t - 1] : 0.f;
            float ep = t < TSTEPS - 1 ? e_row[t + 1] : 0.f;
            r = w0 * em + w1 * e + w2 * ep + ab;
        } else r = 0.f;
        out[b * TSTEPS + t] = r;
    }
}

extern "C" void kernel_launch(void* const* d_in, const int* in_sizes, int n_in,
                              void* d_out, int out_size, void* d_ws, size_t ws_size,
                              hipStream_t stream) {
    (void)in_sizes; (void)n_in; (void)out_size; (void)ws_size;
    const float* z      = (const float*)d_in[0];
    const int* labels   = (const int*)d_in[1];
    const float* emb_W  = (const float*)d_in[2];
    const float* np_W   = (const float*)d_in[3];
    const float* np_b   = (const float*)d_in[4];
    const float* np_g   = (const float*)d_in[5];
    const float* np_be  = (const float*)d_in[6];
    const float* Wih0   = (const float*)d_in[7];
    const float* Whh0   = (const float*)d_in[8];
    const float* bih0   = (const float*)d_in[9];
    const float* bhh0   = (const float*)d_in[10];
    const float* Wih1   = (const float*)d_in[11];
    const float* Whh1   = (const float*)d_in[12];
    const float* bih1   = (const float*)d_in[13];
    const float* bhh1   = (const float*)d_in[14];
    const float* oW1    = (const float*)d_in[15];
    const float* ob1    = (const float*)d_in[16];
    const float* og     = (const float*)d_in[17];
    const float* obe    = (const float*)d_in[18];
    const float* oW2    = (const float*)d_in[19];
    const float* ob2    = (const float*)d_in[20];
    const float* sW1    = (const float*)d_in[21];
    const float* sb1    = (const float*)d_in[22];
    const float* sg     = (const float*)d_in[23];
    const float* sbe    = (const float*)d_in[24];
    const float* sW2    = (const float*)d_in[25];
    const float* sb2    = (const float*)d_in[26];
    const float* stressw= (const float*)d_in[27];
    const float* amu_w  = (const float*)d_in[28];
    const float* amu_b  = (const float*)d_in[29];
    float* out = (float*)d_out;

    uint8_t* ws = (uint8_t*)d_ws;
    size_t off = 0;
    unsigned short* whh0h = (unsigned short*)(ws + off); off += (size_t)1024 * 256 * 2;  // 512KB
    unsigned short* whh0l = (unsigned short*)(ws + off); off += (size_t)1024 * 256 * 2;
    unsigned short* w1h   = (unsigned short*)(ws + off); off += (size_t)1024 * 512 * 2;  // 1MB
    unsigned short* w1l   = (unsigned short*)(ws + off); off += (size_t)1024 * 512 * 2;
    float* Wih0T4 = (float*)(ws + off); off += (size_t)1024 * 512 * 4;                   // 2MB
    float* x_const= (float*)(ws + off); off += (size_t)NB * 512 * 4;
    float* xw0    = (float*)(ws + off); off += (size_t)NB * 1024 * 4;
    float* b1sum  = (float*)(ws + off); off += (size_t)1024 * 4;
    float* hsum   = (float*)(ws + off); off += (size_t)NB * 256 * 4;
    float* basef  = (float*)(ws + off); off += (size_t)NB * TSTEPS * 4;
    unsigned short* hbuf = (unsigned short*)(ws + off); off += (size_t)8 * 2 * 2 * 2 * 4096 * 2; // 512KB
    unsigned* ctrs = (unsigned*)(ws + off); off += 256;

    init_ctrs<<<1, 64, 0, stream>>>(ctrs);
    pack_bf16_frag<<<1024, 256, 0, stream>>>(Whh0, nullptr, 1024, 256, 0, whh0h, whh0l);
    pack_bf16_frag<<<2048, 256, 0, stream>>>(Wih1, Whh1, 1024, 256, 256, w1h, w1l);
    pack4T<<<2048, 256, 0, stream>>>(Wih0, 1024, 512, Wih0T4);
    prep_b1<<<4, 256, 0, stream>>>(bih1, bhh1, b1sum);

    np_head<<<NB, 256, 0, stream>>>(z, labels, emb_W, np_W, np_b, np_g, np_be, x_const);
    xw0_kernel<<<NB, 1024, 0, stream>>>(x_const, (const float4*)Wih0T4, bih0, bhh0, xw0);
    lstm_split<<<64, 192, 131072, stream>>>((const uint4*)whh0h, (const uint4*)whh0l,
                                            (const uint4*)w1h, (const uint4*)w1l,
                                            sW1, xw0, b1sum, sb1, sg, sbe, sW2, sb2,
                                            hbuf, ctrs, basef, hsum);
    out_kernel<<<NB, 256, 0, stream>>>(hsum, oW1, ob1, og, obe, oW2, ob2, basef, labels,
                                       stressw, amu_w, amu_b, out);
}

// Round 5
// 23975.655 us; speedup vs baseline: 4.6567x; 4.6567x over previous
//
#include <hip/hip_runtime.h>

#define TSTEPS 1920
#define NB 128
#define HIDN 256
#define LATN 128
#define EPSF 1e-5f

typedef __attribute__((ext_vector_type(8))) short bf16x8;
typedef __attribute__((ext_vector_type(4))) float f32x4;

__device__ __forceinline__ unsigned short f2bf(float x) {
    unsigned u = __builtin_bit_cast(unsigned, x);
    unsigned r = (u + 0x7fffu + ((u >> 16) & 1u)) >> 16;
    return (unsigned short)r;
}
__device__ __forceinline__ float bf2f(unsigned short h) {
    unsigned u = ((unsigned)h) << 16;
    return __builtin_bit_cast(float, u);
}
__device__ __forceinline__ float fsig(float x) {
    float e = __expf(-fabsf(x));
    float s = 1.f / (1.f + e);
    return x >= 0.f ? s : 1.f - s;
}
__device__ __forceinline__ float ftanh(float x) {
    float e = __expf(-2.f * fabsf(x));
    float r = (1.f - e) / (1.f + e);
    return x >= 0.f ? r : -r;
}
__device__ __forceinline__ float fleaky(float x) { return x > 0.f ? x : 0.2f * x; }
__device__ __forceinline__ bf16x8 bcast16(uint4 v) { return __builtin_bit_cast(bf16x8, v); }

__device__ __forceinline__ unsigned aload(const unsigned* p) {
    return __hip_atomic_load(p, __ATOMIC_RELAXED, __HIP_MEMORY_SCOPE_AGENT);
}
__device__ __forceinline__ void astore(unsigned* p, unsigned v) {
    __hip_atomic_store(p, v, __ATOMIC_RELAXED, __HIP_MEMORY_SCOPE_AGENT);
}

#define MFMA(a, b, c) __builtin_amdgcn_mfma_f32_16x16x32_bf16((a), (b), (c), 0, 0, 0)

// flags: [phase][group][slice] stride 32 u32 (128B pad)
#define FLG(ph, g, s) (((ph) * 8 + (g)) * 8 + (s)) * 32
// hbuf u32 planes: [(g*2+layer)*2+buf][16][256]
#define HPLANE(g, layer, buf) (((g) * 2 + (layer)) * 2 + (buf)) * 4096

// ---- init: zero hbuf (131072 u32) + flags (4096 u32) ----
__global__ void init_sync(unsigned* hbuf, unsigned* flags) {
    int i = blockIdx.x * 256 + threadIdx.x;
    if (i < 131072) hbuf[i] = 0u;
    if (i < 4096) flags[i] = 0u;
}

// ---- pack W [1024][KA+KB] -> sliced MFMA B-frag order, hi/lo bf16 ----
// e = (((w*8+v)*KT + kt)*64 + l)*8 + j ; n = (v>>1)*256 + 32*w + 16*(v&1) + (l&15)
// k = kt*32 + (l>>4)*8 + j
__global__ void pack_bfrag_sliced(const float* __restrict__ A, const float* __restrict__ Bsrc,
                                  int KA, int KB,
                                  unsigned short* __restrict__ hi, unsigned short* __restrict__ lo) {
    int e = blockIdx.x * 256 + threadIdx.x;
    int K = KA + KB;
    int KT = K >> 5;
    if (e >= 1024 * K) return;
    int j = e & 7;
    int l = (e >> 3) & 63;
    int r = e >> 9;
    int kt = r % KT;
    int r2 = r / KT;
    int v = r2 & 7;
    int w = r2 >> 3;
    int n = (v >> 1) * 256 + 32 * w + 16 * (v & 1) + (l & 15);
    int k = kt * 32 + (l >> 4) * 8 + j;
    float val = (k < KA) ? A[n * KA + k] : Bsrc[n * KB + (k - KA)];
    unsigned short h = f2bf(val);
    hi[e] = h;
    lo[e] = f2bf(val - bf2f(h));
}

// ---- pack sW1 [128][256] -> [k][j] bf16-hi ----
__global__ void pack_sw1kj(const float* __restrict__ sW1, unsigned short* __restrict__ out) {
    int e = blockIdx.x * 256 + threadIdx.x;
    if (e >= 256 * 128) return;
    int j = e & 127, k = e >> 7;
    out[e] = f2bf(sW1[j * 256 + k]);
}

// ---- pack fp32 [N][K] -> [k4][n][4] for xw0 GEMV ----
__global__ void pack4T(const float* __restrict__ W, int N, int K, float* __restrict__ out) {
    int e = blockIdx.x * 256 + threadIdx.x;
    if (e >= N * K) return;
    int j = e & 3;
    int rest = e >> 2;
    int n = rest % N;
    int k4 = rest / N;
    out[e] = W[n * K + 4 * k4 + j];
}

__global__ void prep_b1(const float* __restrict__ bih1, const float* __restrict__ bhh1,
                        float* __restrict__ b1sum) {
    int i = blockIdx.x * 256 + threadIdx.x;
    if (i < 1024) b1sum[i] = bih1[i] + bhh1[i];
}

// ---- np head ----
__global__ void np_head(const float* __restrict__ z, const int* __restrict__ labels,
                        const float* __restrict__ emb_W, const float* __restrict__ np_W,
                        const float* __restrict__ np_b, const float* __restrict__ np_g,
                        const float* __restrict__ np_be, float* __restrict__ x_const) {
    int b = blockIdx.x;
    int j = threadIdx.x;
    __shared__ float xc[LATN + HIDN];
    __shared__ float red[8];
    int lab = labels[b];
    if (j < LATN) xc[j] = z[b * LATN + j];
    float e = emb_W[lab * HIDN + j];
    xc[LATN + j] = e;
    __syncthreads();
    float d = np_b[j];
    for (int k = 0; k < LATN + HIDN; ++k) d += xc[k] * np_W[j * (LATN + HIDN) + k];
    int lane = j & 63, wv = j >> 6;
    float s = d, s2 = d * d;
    for (int o = 1; o < 64; o <<= 1) { s += __shfl_xor(s, o); s2 += __shfl_xor(s2, o); }
    if (lane == 0) { red[wv] = s; red[4 + wv] = s2; }
    __syncthreads();
    float S = red[0] + red[1] + red[2] + red[3];
    float S2 = red[4] + red[5] + red[6] + red[7];
    float m = S * (1.f / 256.f);
    float var = S2 * (1.f / 256.f) - m * m;
    float h = fleaky((d - m) * rsqrtf(var + EPSF) * np_g[j] + np_be[j]);
    x_const[b * 512 + j] = h;
    x_const[b * 512 + 256 + j] = e;
}

// ---- xw0 ----
__global__ void __launch_bounds__(1024) xw0_kernel(const float* __restrict__ x_const,
                                                   const float4* __restrict__ Wih0T4,
                                                   const float* __restrict__ bih0,
                                                   const float* __restrict__ bhh0,
                                                   float* __restrict__ xw0) {
    int b = blockIdx.x;
    int g = threadIdx.x;
    __shared__ float xc[512];
    if (g < 512) xc[g] = x_const[b * 512 + g];
    __syncthreads();
    const float4* xc4 = (const float4*)xc;
    float4 acc = {0.f, 0.f, 0.f, 0.f};
#pragma unroll 8
    for (int k4 = 0; k4 < 128; ++k4) {
        float4 w = Wih0T4[k4 * 1024 + g];
        float4 x = xc4[k4];
        acc.x = fmaf(w.x, x.x, acc.x);
        acc.y = fmaf(w.y, x.y, acc.y);
        acc.z = fmaf(w.z, x.z, acc.z);
        acc.w = fmaf(w.w, x.w, acc.w);
    }
    xw0[b * 1024 + g] = bih0[g] + bhh0[g] + ((acc.x + acc.y) + (acc.z + acc.w));
}

// ==== main recurrent kernel: 64 blocks (8 XCD-groups x 8 slices) x 512 thr ====
__global__ void __launch_bounds__(512, 2) lstm_coop(
    const uint4* __restrict__ whh0h, const uint4* __restrict__ whh0l,
    const uint4* __restrict__ w1h, const uint4* __restrict__ w1l,
    const unsigned short* __restrict__ sw1kj_g, const float* __restrict__ xw0g,
    const float* __restrict__ b1sum, const float* __restrict__ sb1,
    const float* __restrict__ sg, const float* __restrict__ sbe,
    const float* __restrict__ sW2, const float* __restrict__ sb2,
    unsigned* __restrict__ hbuf, unsigned* __restrict__ flags,
    float* __restrict__ base_out, float* __restrict__ hsum_out) {
    extern __shared__ char smem[];
    unsigned short* hhi = (unsigned short*)smem;              // [16][512] 16KB
    unsigned short* hlo = (unsigned short*)(smem + 16384);    // 16KB
    unsigned short* sw1s = (unsigned short*)(smem + 32768);   // [256][128] 64KB
    float* gatesL = (float*)(smem + 98304);                   // [16][132] 8448B
    float* ppart = (float*)(smem + 106752);                   // [2][4][128] 4KB
    char* hhiB = smem;
    char* hloB = smem + 16384;

    const int gidx = blockIdx.x & 7;   // group (== XCD if round-robin)
    const int W = blockIdx.x >> 3;     // slice 0..7
    const int g16 = gidx * 16;
    const int tid = threadIdx.x;
    const int l = tid & 63;
    const int v = tid >> 6;            // wave 0..7
    const int ln16 = l & 15;
    const int kg = l >> 4;

    // ---- stage sW1 -> LDS; zero h planes ----
    for (int i = tid; i < 256 * 128; i += 512) sw1s[i] = sw1kj_g[i];
    for (int i = tid; i < 8192; i += 512) { hhi[i] = 0; hlo[i] = 0; }

    // ---- preload layer0 B-frags (16 uint4 = 64 VGPR) ----
    uint4 b0h[8], b0l[8];
#pragma unroll
    for (int kt = 0; kt < 8; ++kt) {
        int idx = ((W * 8 + v) * 8 + kt) * 64 + l;
        b0h[kt] = whh0h[idx];
        b0l[kt] = whh0l[idx];
    }
    // layer1 B-frag base
    const uint4* w1hb = w1h + ((W * 8 + v) * 16) * 64 + l;
    const uint4* w1lb = w1l + ((W * 8 + v) * 16) * 64 + l;

    // ---- per-thread UPD state ----
    const int row = tid >> 5;          // 0..15
    const int ul = tid & 31;
    const int ug = 32 * W + ul;
    float xwi[4], b1v[4];
#pragma unroll
    for (int gt = 0; gt < 4; ++gt) {
        xwi[gt] = xw0g[(g16 + row) * 1024 + gt * 256 + ug];
        b1v[gt] = b1sum[gt * 256 + ug];
    }
    float c0 = 0.f, c1 = 0.f, hs = 0.f;

    // ---- head constants (waves 0,1 use) ----
    const float sb1a = sb1[l], sb1b = sb1[64 + l];
    const float sga = sg[l], sgb = sg[64 + l];
    const float sbea = sbe[l], sbeb = sbe[64 + l];
    const float sw2a = sW2[l], sw2b = sW2[64 + l];
    const float sb2v = sb2[0];

    // hbuf plane bases (u32)
    unsigned* h0buf[2] = {hbuf + HPLANE(gidx, 0, 0), hbuf + HPLANE(gidx, 0, 1)};
    unsigned* h1buf[2] = {hbuf + HPLANE(gidx, 1, 0), hbuf + HPLANE(gidx, 1, 1)};
    unsigned* fl0 = flags + FLG(0, gidx, W);
    unsigned* fl1 = flags + FLG(1, gidx, W);
    unsigned* fl0base = flags + FLG(0, gidx, 0);
    unsigned* fl1base = flags + FLG(1, gidx, 0);

    const int abase = ln16 * 1024;
    const int aswz = (ln16 & 7) << 4;
    const int kgo = kg * 16;
    const int gcol = (v >> 1) * 32 + (v & 1) * 16 + ln16;
    const int hprow = 2 * W + (v & 1);  // head partial row (plane row)
    const int hpswz = (hprow & 7) << 4;
    const int kq = v >> 1;

    __syncthreads();  // P0

    for (int t = 0; t < TSTEPS; ++t) {
        const int cur = t & 1, prev = cur ^ 1;
        // ---- stage h1(t-1) -> planes [256,512) ----
        {
            unsigned* src = h1buf[prev];
            for (int i = tid; i < 4096; i += 512) {
                int r_ = i >> 8, u_ = i & 255;
                unsigned val = aload(src + i);
                int off = r_ * 1024 + ((512 + 2 * u_) ^ ((r_ & 7) << 4));
                *(unsigned short*)(hhiB + off) = (unsigned short)(val >> 16);
                *(unsigned short*)(hloB + off) = (unsigned short)(val & 0xffffu);
            }
        }
        __syncthreads();  // S1
        // ---- MV0 (reads h0(t-1) planes [0,256)) ; head partials (h1(t-1)) ----
        {
            f32x4 acc = {0.f, 0.f, 0.f, 0.f};
#pragma unroll
            for (int kt = 0; kt < 8; ++kt) {
                int aoff = abase + ((kt * 64 + kgo) ^ aswz);
                bf16x8 ahi = bcast16(*(const uint4*)(hhiB + aoff));
                bf16x8 alo = bcast16(*(const uint4*)(hloB + aoff));
                bf16x8 bh = bcast16(b0h[kt]);
                bf16x8 bl = bcast16(b0l[kt]);
                acc = MFMA(ahi, bh, acc);
                acc = MFMA(alo, bh, acc);
                acc = MFMA(ahi, bl, acc);
            }
#pragma unroll
            for (int r = 0; r < 4; ++r) gatesL[(kg * 4 + r) * 132 + gcol] = acc[r];
        }
        if (t > 0) {
            // head partial: row hprow, k in [kq*64, kq*64+64), j = l / 64+l
            float accA = 0.f, accB = 0.f;
            int hb = hprow * 1024;
#pragma unroll 4
            for (int k = kq * 64; k < kq * 64 + 64; ++k) {
                int off = hb + ((512 + 2 * k) ^ hpswz);
                float h = bf2f(*(const unsigned short*)(hhiB + off)) +
                          bf2f(*(const unsigned short*)(hloB + off));
                float wA = bf2f(sw1s[k * 128 + l]);
                float wB = bf2f(sw1s[k * 128 + 64 + l]);
                accA = fmaf(wA, h, accA);
                accB = fmaf(wB, h, accB);
            }
            ppart[(v & 1) * 512 + kq * 128 + l] = accA;
            ppart[(v & 1) * 512 + kq * 128 + 64 + l] = accB;
        }
        __syncthreads();  // S2
        // ---- UPD0: gates -> c0, h0(t) -> hbuf0[cur] ----
        {
            float i_ = gatesL[row * 132 + ul] + xwi[0];
            float f_ = gatesL[row * 132 + 32 + ul] + xwi[1];
            float g_ = gatesL[row * 132 + 64 + ul] + xwi[2];
            float o_ = gatesL[row * 132 + 96 + ul] + xwi[3];
            c0 = fsig(f_) * c0 + fsig(i_) * ftanh(g_);
            float h = fsig(o_) * ftanh(c0);
            unsigned short hh = f2bf(h);
            unsigned short ll = f2bf(h - bf2f(hh));
            astore(h0buf[cur] + row * 256 + ug, ((unsigned)hh << 16) | (unsigned)ll);
        }
        asm volatile("s_waitcnt vmcnt(0)" ::: "memory");
        __syncthreads();  // S3
        if (tid == 0) astore(fl0, (unsigned)(t + 1));
        {
            unsigned tgt = (unsigned)(t + 1);
            while (true) {
                unsigned val = (l < 8) ? aload(fl0base + l * 32) : tgt;
                if (__all((int)(val >= tgt))) break;
                __builtin_amdgcn_s_sleep(1);
            }
        }
        asm volatile("" ::: "memory");
        // ---- stage h0(t) -> planes [0,256) ----
        {
            unsigned* src = h0buf[cur];
            for (int i = tid; i < 4096; i += 512) {
                int r_ = i >> 8, u_ = i & 255;
                unsigned val = aload(src + i);
                int off = r_ * 1024 + ((2 * u_) ^ ((r_ & 7) << 4));
                *(unsigned short*)(hhiB + off) = (unsigned short)(val >> 16);
                *(unsigned short*)(hloB + off) = (unsigned short)(val & 0xffffu);
            }
        }
        __syncthreads();  // S4
        // ---- MV1: [Wih1|Whh1] @ [h0(t); h1(t-1)] ----
        {
            f32x4 acc = {0.f, 0.f, 0.f, 0.f};
#pragma unroll 4
            for (int kt = 0; kt < 16; ++kt) {
                int aoff = abase + ((kt * 64 + kgo) ^ aswz);
                bf16x8 ahi = bcast16(*(const uint4*)(hhiB + aoff));
                bf16x8 alo = bcast16(*(const uint4*)(hloB + aoff));
                bf16x8 bh = bcast16(w1hb[kt * 64]);
                bf16x8 bl = bcast16(w1lb[kt * 64]);
                acc = MFMA(ahi, bh, acc);
                acc = MFMA(alo, bh, acc);
                acc = MFMA(ahi, bl, acc);
            }
#pragma unroll
            for (int r = 0; r < 4; ++r) gatesL[(kg * 4 + r) * 132 + gcol] = acc[r];
        }
        __syncthreads();  // S5
        // ---- UPD1 ----
        {
            float i_ = gatesL[row * 132 + ul] + b1v[0];
            float f_ = gatesL[row * 132 + 32 + ul] + b1v[1];
            float g_ = gatesL[row * 132 + 64 + ul] + b1v[2];
            float o_ = gatesL[row * 132 + 96 + ul] + b1v[3];
            c1 = fsig(f_) * c1 + fsig(i_) * ftanh(g_);
            float h = fsig(o_) * ftanh(c1);
            hs += h;
            unsigned short hh = f2bf(h);
            unsigned short ll = f2bf(h - bf2f(hh));
            astore(h1buf[cur] + row * 256 + ug, ((unsigned)hh << 16) | (unsigned)ll);
        }
        // ---- head finish (waves 0,1): LN + base(t-1) ----
        if (t > 0 && v < 2) {
            float sA = sb1a, sB = sb1b;
#pragma unroll
            for (int q = 0; q < 4; ++q) {
                sA += ppart[v * 512 + q * 128 + l];
                sB += ppart[v * 512 + q * 128 + 64 + l];
            }
            float ssum = sA + sB, ssq = sA * sA + sB * sB;
#pragma unroll
            for (int o = 1; o < 64; o <<= 1) { ssum += __shfl_xor(ssum, o); ssq += __shfl_xor(ssq, o); }
            float m = ssum * (1.f / 128.f);
            float var = ssq * (1.f / 128.f) - m * m;
            float rstd = rsqrtf(var + EPSF);
            float p0 = fleaky((sA - m) * rstd * sga + sbea);
            float p1 = fleaky((sB - m) * rstd * sgb + sbeb);
            float q = p0 * sw2a + p1 * sw2b;
#pragma unroll
            for (int o = 1; o < 64; o <<= 1) q += __shfl_xor(q, o);
            if (l == 0) base_out[(g16 + 2 * W + v) * TSTEPS + (t - 1)] = ftanh(q + sb2v);
        }
        asm volatile("s_waitcnt vmcnt(0)" ::: "memory");
        __syncthreads();  // S6
        if (tid == 0) astore(fl1, (unsigned)(t + 1));
        {
            unsigned tgt = (unsigned)(t + 1);
            while (true) {
                unsigned val = (l < 8) ? aload(fl1base + l * 32) : tgt;
                if (__all((int)(val >= tgt))) break;
                __builtin_amdgcn_s_sleep(1);
            }
        }
        asm volatile("" ::: "memory");
    }
    // ---- epilogue: head(1919) ----
    {
        unsigned* src = h1buf[(TSTEPS - 1) & 1];
        for (int i = tid; i < 4096; i += 512) {
            int r_ = i >> 8, u_ = i & 255;
            unsigned val = aload(src + i);
            int off = r_ * 1024 + ((512 + 2 * u_) ^ ((r_ & 7) << 4));
            *(unsigned short*)(hhiB + off) = (unsigned short)(val >> 16);
            *(unsigned short*)(hloB + off) = (unsigned short)(val & 0xffffu);
        }
    }
    __syncthreads();  // E1
    {
        float accA = 0.f, accB = 0.f;
        int hb = hprow * 1024;
#pragma unroll 4
        for (int k = kq * 64; k < kq * 64 + 64; ++k) {
            int off = hb + ((512 + 2 * k) ^ hpswz);
            float h = bf2f(*(const unsigned short*)(hhiB + off)) +
                      bf2f(*(const unsigned short*)(hloB + off));
            accA = fmaf(bf2f(sw1s[k * 128 + l]), h, accA);
            accB = fmaf(bf2f(sw1s[k * 128 + 64 + l]), h, accB);
        }
        ppart[(v & 1) * 512 + kq * 128 + l] = accA;
        ppart[(v & 1) * 512 + kq * 128 + 64 + l] = accB;
    }
    __syncthreads();  // E2
    if (v < 2) {
        float sA = sb1a, sB = sb1b;
#pragma unroll
        for (int q = 0; q < 4; ++q) {
            sA += ppart[v * 512 + q * 128 + l];
            sB += ppart[v * 512 + q * 128 + 64 + l];
        }
        float ssum = sA + sB, ssq = sA * sA + sB * sB;
#pragma unroll
        for (int o = 1; o < 64; o <<= 1) { ssum += __shfl_xor(ssum, o); ssq += __shfl_xor(ssq, o); }
        float m = ssum * (1.f / 128.f);
        float var = ssq * (1.f / 128.f) - m * m;
        float rstd = rsqrtf(var + EPSF);
        float p0 = fleaky((sA - m) * rstd * sga + sbea);
        float p1 = fleaky((sB - m) * rstd * sgb + sbeb);
        float q = p0 * sw2a + p1 * sw2b;
#pragma unroll
        for (int o = 1; o < 64; o <<= 1) q += __shfl_xor(q, o);
        if (l == 0) base_out[(g16 + 2 * W + v) * TSTEPS + (TSTEPS - 1)] = ftanh(q + sb2v);
    }
    hsum_out[(g16 + row) * HIDN + ug] = hs;
}

// ---- final head + oscillator + smoothing + label select ----
__global__ void out_kernel(const float* __restrict__ hsum, const float* __restrict__ oW1,
                           const float* __restrict__ ob1, const float* __restrict__ og,
                           const float* __restrict__ obe, const float* __restrict__ oW2,
                           const float* __restrict__ ob2, const float* __restrict__ base,
                           const int* __restrict__ labels, const float* __restrict__ stress_w,
                           const float* __restrict__ amu_w, const float* __restrict__ amu_b,
                           float* __restrict__ out) {
    int b = blockIdx.x;
    int tid = threadIdx.x;
    int lane = tid & 63, wv = tid >> 6;
    __shared__ float havg[256];
    __shared__ float red[8];
    __shared__ float params[3];
    __shared__ float e_row[TSTEPS];
    havg[tid] = hsum[b * 256 + tid] * (1.f / (float)TSTEPS);
    __syncthreads();
    float d1 = 0.f;
    if (tid < 128) {
        d1 = ob1[tid];
        for (int k = 0; k < 256; ++k) d1 += havg[k] * oW1[tid * 256 + k];
    }
    float s = d1, s2 = d1 * d1;
    for (int o = 1; o < 64; o <<= 1) { s += __shfl_xor(s, o); s2 += __shfl_xor(s2, o); }
    if (lane == 0 && wv < 2) { red[wv] = s; red[2 + wv] = s2; }
    __syncthreads();
    float m = (red[0] + red[1]) * (1.f / 128.f);
    float var = (red[2] + red[3]) * (1.f / 128.f) - m * m;
    float rstd = rsqrtf(var + EPSF);
    float p = 0.f;
    if (tid < 128) p = fleaky((d1 - m) * rstd * og[tid] + obe[tid]);
    float q0 = tid < 128 ? p * oW2[0 * 128 + tid] : 0.f;
    float q1 = tid < 128 ? p * oW2[1 * 128 + tid] : 0.f;
    float q2 = tid < 128 ? p * oW2[2 * 128 + tid] : 0.f;
    for (int o = 1; o < 64; o <<= 1) {
        q0 += __shfl_xor(q0, o); q1 += __shfl_xor(q1, o); q2 += __shfl_xor(q2, o);
    }
    __syncthreads();
    if (lane == 0 && wv < 2) { red[wv] = q0; red[2 + wv] = q1; red[4 + wv] = q2; }
    __syncthreads();
    if (tid == 0) {
        float op0 = red[0] + red[1] + ob2[0];
        float op1 = red[2] + red[3] + ob2[1];
        float op2 = red[4] + red[5] + ob2[2];
        params[0] = 0.23f + 0.04f * ftanh(op0);
        params[1] = 2.0f + 1.5f * ftanh(op1);
        params[2] = 3.14159265358979f * fsig(op2);
    }
    __syncthreads();
    float freq = params[0], amp = params[1], ph = params[2];
    for (int t = tid; t < TSTEPS; t += 256) {
        float x = freq * ((float)TSTEPS * (float)t / (float)(TSTEPS - 1));
        x -= floorf(x);
        float osc = amp * __sinf(6.28318530717958647f * x + ph);
        e_row[t] = 0.6f * base[b * TSTEPS + t] + 0.4f * osc;
    }
    __syncthreads();
    int lab = labels[b];
    float sw = stress_w[0];
    float w0 = amu_w[0], w1 = amu_w[1], w2 = amu_w[2], ab = amu_b[0];
    for (int t = tid; t < TSTEPS; t += 256) {
        float e = e_row[t];
        float r;
        if (lab == 1) r = e;
        else if (lab == 2) r = sw * e;
        else if (lab == 3) {
            float em = t > 0 ? e_row[t - 1] : 0.f;
            float ep = t < TSTEPS - 1 ? e_row[t + 1] : 0.f;
            r = w0 * em + w1 * e + w2 * ep + ab;
        } else r = 0.f;
        out[b * TSTEPS + t] = r;
    }
}

extern "C" void kernel_launch(void* const* d_in, const int* in_sizes, int n_in,
                              void* d_out, int out_size, void* d_ws, size_t ws_size,
                              hipStream_t stream) {
    (void)in_sizes; (void)n_in; (void)out_size; (void)ws_size;
    const float* z      = (const float*)d_in[0];
    const int* labels   = (const int*)d_in[1];
    const float* emb_W  = (const float*)d_in[2];
    const float* np_W   = (const float*)d_in[3];
    const float* np_b   = (const float*)d_in[4];
    const float* np_g   = (const float*)d_in[5];
    const float* np_be  = (const float*)d_in[6];
    const float* Wih0   = (const float*)d_in[7];
    const float* Whh0   = (const float*)d_in[8];
    const float* bih0   = (const float*)d_in[9];
    const float* bhh0   = (const float*)d_in[10];
    const float* Wih1   = (const float*)d_in[11];
    const float* Whh1   = (const float*)d_in[12];
    const float* bih1   = (const float*)d_in[13];
    const float* bhh1   = (const float*)d_in[14];
    const float* oW1    = (const float*)d_in[15];
    const float* ob1    = (const float*)d_in[16];
    const float* og     = (const float*)d_in[17];
    const float* obe    = (const float*)d_in[18];
    const float* oW2    = (const float*)d_in[19];
    const float* ob2    = (const float*)d_in[20];
    const float* sW1    = (const float*)d_in[21];
    const float* sb1    = (const float*)d_in[22];
    const float* sg     = (const float*)d_in[23];
    const float* sbe    = (const float*)d_in[24];
    const float* sW2    = (const float*)d_in[25];
    const float* sb2    = (const float*)d_in[26];
    const float* stressw= (const float*)d_in[27];
    const float* amu_w  = (const float*)d_in[28];
    const float* amu_b  = (const float*)d_in[29];
    float* out = (float*)d_out;

    uint8_t* ws = (uint8_t*)d_ws;
    size_t off = 0;
    unsigned short* whh0h = (unsigned short*)(ws + off); off += (size_t)1024 * 256 * 2;
    unsigned short* whh0l = (unsigned short*)(ws + off); off += (size_t)1024 * 256 * 2;
    unsigned short* w1h   = (unsigned short*)(ws + off); off += (size_t)1024 * 512 * 2;
    unsigned short* w1l   = (unsigned short*)(ws + off); off += (size_t)1024 * 512 * 2;
    unsigned short* sw1kj = (unsigned short*)(ws + off); off += (size_t)256 * 128 * 2;
    float* Wih0T4 = (float*)(ws + off); off += (size_t)1024 * 512 * 4;
    float* x_const= (float*)(ws + off); off += (size_t)NB * 512 * 4;
    float* xw0    = (float*)(ws + off); off += (size_t)NB * 1024 * 4;
    float* b1sum  = (float*)(ws + off); off += (size_t)1024 * 4;
    float* hsum   = (float*)(ws + off); off += (size_t)NB * 256 * 4;
    float* basef  = (float*)(ws + off); off += (size_t)NB * TSTEPS * 4;
    off = (off + 255) & ~(size_t)255;
    unsigned* hbuf = (unsigned*)(ws + off); off += (size_t)131072 * 4;   // 512KB
    unsigned* flags= (unsigned*)(ws + off); off += (size_t)4096 * 4;     // 16KB

    init_sync<<<512, 256, 0, stream>>>(hbuf, flags);
    pack_bfrag_sliced<<<1024, 256, 0, stream>>>(Whh0, nullptr, 256, 0, whh0h, whh0l);
    pack_bfrag_sliced<<<2048, 256, 0, stream>>>(Wih1, Whh1, 256, 256, w1h, w1l);
    pack_sw1kj<<<128, 256, 0, stream>>>(sW1, sw1kj);
    pack4T<<<2048, 256, 0, stream>>>(Wih0, 1024, 512, Wih0T4);
    prep_b1<<<4, 256, 0, stream>>>(bih1, bhh1, b1sum);

    np_head<<<NB, 256, 0, stream>>>(z, labels, emb_W, np_W, np_b, np_g, np_be, x_const);
    xw0_kernel<<<NB, 1024, 0, stream>>>(x_const, (const float4*)Wih0T4, bih0, bhh0, xw0);
    lstm_coop<<<64, 512, 110848, stream>>>((const uint4*)whh0h, (const uint4*)whh0l,
                                           (const uint4*)w1h, (const uint4*)w1l,
                                           sw1kj, xw0, b1sum, sb1, sg, sbe, sW2, sb2,
                                           hbuf, flags, basef, hsum);
    out_kernel<<<NB, 256, 0, stream>>>(hsum, oW1, ob1, og, obe, oW2, ob2, basef, labels,
                                       stressw, amu_w, amu_b, out);
}